// Round 3
// baseline (1308.332 us; speedup 1.0000x reference)
//
#include <hip/hip_runtime.h>

#define B_ 32
#define C_ 384
#define TX_ 512
#define TY_ 2048
#define KW_ 3
#define EPS_ 1e-5f
#define LAY_ ((size_t)(36 * 1536 * 8))   // shorts per packed conv layer (442368)

typedef __attribute__((ext_vector_type(8))) short short8;
typedef __attribute__((ext_vector_type(4))) float f32x4;

#define MFMA(a, b, c) __builtin_amdgcn_mfma_f32_16x16x32_bf16(a, b, c, 0, 0, 0)

__device__ inline unsigned short f2bf(float f) {
    union { float f; unsigned int u; } v; v.f = f;
    unsigned int r = v.u + 0x7fffu + ((v.u >> 16) & 1u);
    return (unsigned short)(r >> 16);
}
__device__ inline float bf2f(unsigned short s) {
    union { float f; unsigned int u; } v; v.u = ((unsigned int)s) << 16;
    return v.f;
}

template<bool INBF>
__device__ inline float ldx(const void* p, size_t i) {
    if constexpr (INBF) return bf2f(((const unsigned short*)p)[i]);
    else return ((const float*)p)[i];
}

// ---- pack conv weights f32 [NL][O][I][K] -> fragment-linear bf16, folding LN gamma:
// granule G = ((lay*36 + c)*384 + o)*4 + lg, c = k*12+ib; elems e: W[o][i][k]*g[i],
// i = ib*32 + lg*8 + e.
__global__ __launch_bounds__(256) void pack_w2(const float* cw0, const float* cw1,
                                               const float* cw2, const float* g0,
                                               const float* g1, const float* g2,
                                               unsigned short* wp) {
    int idx = blockIdx.x * 256 + threadIdx.x;
    const int NG = 6 * 36 * 384 * 4;
    if (idx >= NG) return;
    int lg = idx & 3;
    int o = (idx >> 2) % 384;
    int c = ((idx >> 2) / 384) % 36;
    int lay = (idx >> 2) / (384 * 36);
    int k = c / 12, ib = c % 12;
    int pr = lay >> 1, l = lay & 1;
    const float* cw = ((pr == 0) ? cw0 : (pr == 1) ? cw1 : cw2) + (size_t)l * C_ * C_ * KW_;
    const float* g  = ((pr == 0) ? g0  : (pr == 1) ? g1  : g2)  + (size_t)l * C_;
    const int i0 = ib * 32 + lg * 8;
    short8 v;
    #pragma unroll
    for (int e = 0; e < 8; e++)
        v[e] = (short)f2bf(cw[((size_t)o * C_ + i0 + e) * KW_ + k] * g[i0 + e]);
    *(short8*)&wp[(size_t)idx * 8] = v;
}

// ---- fold LN beta into conv bias: biasT[lay][o] = cb[o] + sum_{i,k} W[o,i,k]*beta[i];
// bc0/bc2 hold the k=0 / k=2 partial sums for boundary-column correction.
__global__ __launch_bounds__(256) void bias_fold(
    const float* cw0, const float* cw1, const float* cw2,
    const float* be0, const float* be1, const float* be2,
    const float* cb0, const float* cb1, const float* cb2,
    float* biasT, float* bc0, float* bc2) {
    int idx = blockIdx.x * 256 + threadIdx.x;
    if (idx >= 6 * 384) return;
    int o = idx % 384, lay = idx / 384;
    int pr = lay >> 1, l = lay & 1;
    const float* cw = ((pr == 0) ? cw0 : (pr == 1) ? cw1 : cw2)
                      + (size_t)l * C_ * C_ * KW_ + (size_t)o * C_ * KW_;
    const float* be = ((pr == 0) ? be0 : (pr == 1) ? be1 : be2) + (size_t)l * C_;
    const float* cb = ((pr == 0) ? cb0 : (pr == 1) ? cb1 : cb2) + (size_t)l * C_;
    float s0 = 0.f, s1 = 0.f, s2 = 0.f;
    for (int i = 0; i < C_; i++) {
        const float b = be[i];
        s0 += cw[i * 3 + 0] * b; s1 += cw[i * 3 + 1] * b; s2 += cw[i * 3 + 2] * b;
    }
    biasT[idx] = cb[o] + s0 + s1 + s2;
    bc0[idx] = s0; bc2[idx] = s2;
}

// ---- pack x f32 [B][C][TX] -> fragment-linear bf16 for bmm A-operand
__global__ __launch_bounds__(256) void pack_x2(const float* x, unsigned short* xp) {
    int idx = blockIdx.x * 256 + threadIdx.x;
    const int NG = B_ * 16 * 384 * 4;
    if (idx >= NG) return;
    int lg = idx & 3;
    int c = (idx >> 2) % 384;
    int q = ((idx >> 2) / 384) % 16;
    int b = (idx >> 2) / (384 * 16);
    const float* src = x + ((size_t)b * C_ + c) * TX_ + q * 32 + lg * 8;
    short8 v;
    #pragma unroll
    for (int e = 0; e < 8; e++) v[e] = (short)f2bf(src[e]);
    *(short8*)&xp[(size_t)idx * 8] = v;
}

// ---- LN stats (mean, rstd) over C at each (b,t) of f32 [B,C,T]
__global__ __launch_bounds__(256) void ln_stats_f32(const float* x, float2* st, int T) {
    __shared__ float r1[4][64], r2[4][64];
    int b = blockIdx.y, t0 = blockIdx.x * 64;
    int tl = threadIdx.x & 63, g = threadIdx.x >> 6;
    int t = t0 + tl;
    const float* p = x + (size_t)b * C_ * T + t;
    float s = 0.f, ss = 0.f;
    for (int c = g; c < C_; c += 4) { float v = p[(size_t)c * T]; s += v; ss += v * v; }
    r1[g][tl] = s; r2[g][tl] = ss;
    __syncthreads();
    if (threadIdx.x < 64) {
        float s1 = r1[0][tl] + r1[1][tl] + r1[2][tl] + r1[3][tl];
        float s2 = r2[0][tl] + r2[1][tl] + r2[2][tl] + r2[3][tl];
        float m = s1 * (1.f / C_);
        float var = s2 * (1.f / C_) - m * m;
        st[(size_t)b * T + t0 + tl] = make_float2(m, rsqrtf(var + EPS_));
    }
}

// ---- fused LN(z-only) -> conv1d(K=3) -> bias' -> SiLU -> mask.
// LN gamma/beta folded into W2/biasT (bc0/bc2 fix the zero-padded edges).
// Stages z = (x-m)*r once; runs npass K-loops (pass sel = blockIdx.z + p).
template<bool INBF, bool PRED>
__global__ __launch_bounds__(256, 2) void conv_ln(
    const void* __restrict__ Xin, long Xstride,
    const float2* __restrict__ stin, long stinStride,
    const unsigned short* __restrict__ W2,
    const float* __restrict__ biasT, const float* __restrict__ bc0,
    const float* __restrict__ bc2, int lay0, int laystep,
    const float* __restrict__ mask,
    unsigned short* __restrict__ Hout, long Hstride,
    float2* __restrict__ stout, long stoutStride,
    float* __restrict__ pred, long predStride,
    const float* __restrict__ owA, const float* __restrict__ owB,
    const float* __restrict__ obA, const float* __restrict__ obB,
    int T, int tlog, int npass)
{
    __shared__ __align__(16) unsigned short xs[66 * 384];
    __shared__ float red[128];
    const int tid = threadIdx.x;
    const int z = blockIdx.z;
    const int nx = gridDim.x;
    const int bid = blockIdx.x;
    const int work = (bid & 7) * (nx >> 3) + (bid >> 3);   // XCD-chunked swizzle
    const int b = work >> tlog;
    const int t0 = (work & ((1 << tlog) - 1)) << 6;
    const int lane = tid & 63;
    const int wave = tid >> 6;
    const int lr = lane & 15, lg = lane >> 4;
    const int wm = wave * 96;

    const void* Xz;
    if constexpr (INBF) Xz = (const void*)((const unsigned short*)Xin + (size_t)z * Xstride);
    else                Xz = (const void*)((const float*)Xin + (size_t)z * Xstride);
    const float2* stz = stin + (size_t)z * stinStride;

    // ---- stage z tile: rows tt=0..65 <-> t=t0-1+tt, 384 bf16/row, swizzled 16B granules
    {
        const int tt1 = 1 + lane;
        const int t = t0 + lane;
        const float2 mr = stz[(size_t)b * T + t];
        #pragma unroll
        for (int h = 0; h < 3; ++h) {           // 12 granule-cols/wave in 3 bursts of 4
            float vv[4][8];
            #pragma unroll
            for (int i = 0; i < 4; i++) {
                const int cg = wave + (h * 4 + i) * 4;
                const size_t base = ((size_t)b * C_ + cg * 8) * T + t;
                #pragma unroll
                for (int j = 0; j < 8; j++) vv[i][j] = ldx<INBF>(Xz, base + (size_t)j * T);
            }
            #pragma unroll
            for (int i = 0; i < 4; i++) {
                const int cg = wave + (h * 4 + i) * 4;
                short8 v8;
                #pragma unroll
                for (int j = 0; j < 8; j++) v8[j] = (short)f2bf((vv[i][j] - mr.x) * mr.y);
                const int ph = (cg & ~7) | ((cg ^ tt1) & 7);
                *(short8*)&xs[tt1 * 384 + ph * 8] = v8;
            }
        }
        if (tid < 96) {  // halo rows (zero-padded SAME conv)
            const int tt2 = (tid < 48) ? 0 : 65;
            const int cg = tid % 48;
            const int t2 = t0 - 1 + tt2;
            short8 v8;
            if (t2 >= 0 && t2 < T) {
                const float2 mr2 = stz[(size_t)b * T + t2];
                const size_t base = ((size_t)b * C_ + cg * 8) * T + t2;
                #pragma unroll
                for (int j = 0; j < 8; j++)
                    v8[j] = (short)f2bf((ldx<INBF>(Xz, base + (size_t)j * T) - mr2.x) * mr2.y);
            } else {
                #pragma unroll
                for (int j = 0; j < 8; j++) v8[j] = 0;
            }
            const int ph = (cg & ~7) | ((cg ^ tt2) & 7);
            *(short8*)&xs[tt2 * 384 + ph * 8] = v8;
        }
    }
    __syncthreads();

    for (int p = 0; p < npass; ++p) {
        const int sel = z + p;
        const int lay = lay0 + sel * laystep;

        f32x4 acc[6][4];
        const f32x4 zero = {0.f, 0.f, 0.f, 0.f};
        #pragma unroll
        for (int fm = 0; fm < 6; fm++)
            #pragma unroll
            for (int fn = 0; fn < 4; fn++) acc[fm][fn] = zero;

        const unsigned short* wbase = W2 + (size_t)lay * LAY_
                                      + (size_t)((wm + lr) * 4 + lg) * 8;
        short8 afA[6], afB[6], bfA[4], bfB[4];

        auto LOADAF = [&](short8* dst, int c) {
            #pragma unroll
            for (int fm = 0; fm < 6; fm++)
                dst[fm] = *(const short8*)(wbase + (size_t)c * 12288 + fm * 512);
        };
        auto LOADBF = [&](short8* dst, int c) {
            const int k = c / 12, ib = c - k * 12;
            #pragma unroll
            for (int fn = 0; fn < 4; fn++) {
                const int row = k + fn * 16 + lr;
                const int cgi = ib * 4 + lg;
                const int ph = (cgi & ~7) | ((cgi ^ row) & 7);
                dst[fn] = *(const short8*)&xs[row * 384 + ph * 8];
            }
        };
        auto FMAS = [&](short8* af, short8* bf) {
            #pragma unroll
            for (int fm = 0; fm < 6; fm++)
                #pragma unroll
                for (int fn = 0; fn < 4; fn++)
                    acc[fm][fn] = MFMA(af[fm], bf[fn], acc[fm][fn]);
        };

        LOADAF(afA, 0); LOADBF(bfA, 0);
        #pragma unroll
        for (int c = 0; c < 36; c += 2) {
            LOADAF(afB, c + 1); LOADBF(bfB, c + 1);
            FMAS(afA, bfA);
            const int c2 = (c + 2 < 36) ? c + 2 : 35;
            LOADAF(afA, c2); LOADBF(bfA, c2);
            FMAS(afB, bfB);
        }

        // ---- epilogue
        __syncthreads();
        if (tid < 128) red[tid] = 0.f;
        __syncthreads();

        const float* bT = biasT + lay * 384;
        const float* c0 = bc0 + lay * 384;
        const float* c2 = bc2 + lay * 384;
        unsigned short* HoutSel = Hout + (size_t)sel * Hstride;
        const float* owSel = sel ? owB : owA;
        const bool edge = (t0 == 0) || (t0 + 64 == T);

        #pragma unroll
        for (int fn = 0; fn < 4; fn++) {
            const int tl = fn * 16 + lr;
            const int t = t0 + tl;
            const float mk = mask[(size_t)b * T + t];
            float s1 = 0.f, s2 = 0.f;
            #pragma unroll
            for (int fm = 0; fm < 6; fm++) {
                const int o0 = wm + fm * 16 + lg * 4;
                #pragma unroll
                for (int j = 0; j < 4; j++) {
                    float h = acc[fm][fn][j] + bT[o0 + j];
                    if (edge) {
                        if (t == 0) h -= c0[o0 + j];
                        if (t == T - 1) h -= c2[o0 + j];
                    }
                    const float y = h * (1.f / (1.f + __expf(-h))) * mk;
                    if constexpr (!PRED) {
                        HoutSel[((size_t)b * C_ + o0 + j) * T + t] = f2bf(y);
                        s1 += y; s2 += y * y;
                    } else {
                        s1 += y * owSel[o0 + j];
                    }
                }
            }
            if constexpr (!PRED) {
                atomicAdd(&red[tl * 2], s1);
                atomicAdd(&red[tl * 2 + 1], s2);
            } else {
                atomicAdd(&red[tl], s1);
            }
        }
        __syncthreads();
        if (tid < 64) {
            const int t = t0 + tid;
            if constexpr (!PRED) {
                const float s1 = red[tid * 2], s2 = red[tid * 2 + 1];
                const float m = s1 * (1.f / C_);
                const float var = s2 * (1.f / C_) - m * m;
                (stout + (size_t)sel * stoutStride)[(size_t)b * T + t] =
                    make_float2(m, rsqrtf(var + EPS_));
            } else {
                const float ob = (sel ? obB : obA)[0];
                (pred + (size_t)sel * predStride)[(size_t)b * T + t] =
                    (red[tid] + ob) * mask[(size_t)b * T + t];
            }
        }
    }
}

// ---- xe = x @ path (full K=512 in LDS, 32-y tiles); LN stats of xe;
// fused: out = xe+pitch+energy, xebf = bf16(xe)
__global__ __launch_bounds__(256, 2) void bmm_ln(
    const unsigned short* __restrict__ x2, const float* __restrict__ path,
    const float* __restrict__ pitch, const float* __restrict__ energy,
    float* __restrict__ out, unsigned short* __restrict__ xebf,
    float2* __restrict__ stout, int fused)
{
    __shared__ __align__(16) unsigned short ps[32 * 512];   // 32 KB
    const int tid = threadIdx.x;
    const int bid = blockIdx.x;
    const int work = (bid & 7) * 256 + (bid >> 3);          // XCD-chunked swizzle
    const int b = work >> 6;
    const int y0 = (work & 63) << 5;
    const int lane = tid & 63;
    const int wave = tid >> 6;
    const int lr = lane & 15, lg = lane >> 4;
    const int wm = wave * 96;

    // ---- stage path [512 t x 32 y] -> rows y, cols t (bf16, swizzled granules)
    {
        const int yy = lane & 31;
        const int half = lane >> 5;
        const int gbase = (wave * 2 + half) * 8;
        const float* pb = path + (size_t)b * TX_ * TY_ + y0 + yy;
        #pragma unroll
        for (int h = 0; h < 2; ++h) {
            float vv[4][8];
            #pragma unroll
            for (int i = 0; i < 4; i++) {
                const int cg = gbase + h * 4 + i;
                #pragma unroll
                for (int j = 0; j < 8; j++) vv[i][j] = pb[(size_t)(cg * 8 + j) * TY_];
            }
            #pragma unroll
            for (int i = 0; i < 4; i++) {
                const int cg = gbase + h * 4 + i;
                short8 v8;
                #pragma unroll
                for (int j = 0; j < 8; j++) v8[j] = (short)f2bf(vv[i][j]);
                const int ph = (cg & ~7) | ((cg ^ yy) & 7);
                *(short8*)&ps[yy * 512 + ph * 8] = v8;
            }
        }
    }
    __syncthreads();

    f32x4 acc[6][2];
    const f32x4 zero = {0.f, 0.f, 0.f, 0.f};
    #pragma unroll
    for (int fm = 0; fm < 6; fm++) { acc[fm][0] = zero; acc[fm][1] = zero; }

    const unsigned short* xb = x2 + ((size_t)b * 16 * 1536 + (size_t)((wm + lr) * 4 + lg)) * 8;
    short8 afA[6], afB[6], bfA[2], bfB[2];

    auto LOADAF = [&](short8* dst, int q) {
        #pragma unroll
        for (int fm = 0; fm < 6; fm++)
            dst[fm] = *(const short8*)(xb + (size_t)q * 12288 + fm * 512);
    };
    auto LOADBF = [&](short8* dst, int u) {
        #pragma unroll
        for (int fn = 0; fn < 2; fn++) {
            const int row = fn * 16 + lr;
            const int cgi = u * 4 + lg;
            const int ph = (cgi & ~7) | ((cgi ^ row) & 7);
            dst[fn] = *(const short8*)&ps[row * 512 + ph * 8];
        }
    };
    auto FMAS = [&](short8* af, short8* bf) {
        #pragma unroll
        for (int fm = 0; fm < 6; fm++) {
            acc[fm][0] = MFMA(af[fm], bf[0], acc[fm][0]);
            acc[fm][1] = MFMA(af[fm], bf[1], acc[fm][1]);
        }
    };

    LOADAF(afA, 0); LOADBF(bfA, 0);
    #pragma unroll
    for (int u = 0; u < 16; u += 2) {
        LOADAF(afB, u + 1); LOADBF(bfB, u + 1);
        FMAS(afA, bfA);
        const int u2 = (u + 2 < 16) ? u + 2 : 15;
        LOADAF(afA, u2); LOADBF(bfA, u2);
        FMAS(afB, bfB);
    }

    // ---- epilogue
    __syncthreads();
    float* red = (float*)ps;
    if (tid < 64) red[tid] = 0.f;
    __syncthreads();

    #pragma unroll
    for (int fn = 0; fn < 2; fn++) {
        const int yl = fn * 16 + lr;
        const int y = y0 + yl;
        float s1 = 0.f, s2 = 0.f;
        #pragma unroll
        for (int fm = 0; fm < 6; fm++) {
            #pragma unroll
            for (int j = 0; j < 4; j++) {
                const int c = wm + fm * 16 + lg * 4 + j;
                const size_t gi = ((size_t)b * C_ + c) * TY_ + y;
                const float v = acc[fm][fn][j];
                if (fused) {
                    out[gi] = v + pitch[gi] + energy[gi];
                    xebf[gi] = f2bf(v);
                } else {
                    out[gi] = v;
                }
                s1 += v; s2 += v * v;
            }
        }
        atomicAdd(&red[yl * 2], s1);
        atomicAdd(&red[yl * 2 + 1], s2);
    }
    __syncthreads();
    if (tid < 32) {
        const int y = y0 + tid;
        const float s1 = red[tid * 2], s2 = red[tid * 2 + 1];
        const float m = s1 * (1.f / C_);
        const float var = s2 * (1.f / C_) - m * m;
        stout[(size_t)b * TY_ + y] = make_float2(m, rsqrtf(var + EPS_));
    }
}

// ---- out = xe(in place) + pitch + energy   (tier-3 fallback only)
__global__ __launch_bounds__(256) void add3(float4* o, const float4* p, const float4* e, int n4) {
    for (int i = blockIdx.x * 256 + threadIdx.x; i < n4; i += gridDim.x * 256) {
        float4 a = o[i], x1 = p[i], x2 = e[i];
        a.x += x1.x + x2.x; a.y += x1.y + x2.y;
        a.z += x1.z + x2.z; a.w += x1.w + x2.w;
        o[i] = a;
    }
}

extern "C" void kernel_launch(void* const* d_in, const int* in_sizes, int n_in,
                              void* d_out, int out_size, void* d_ws, size_t ws_size,
                              hipStream_t stream)
{
    const float* x      = (const float*)d_in[0];
    const float* x_mask = (const float*)d_in[1];
    const float* y_mask = (const float*)d_in[2];
    const float* pitch  = (const float*)d_in[3];
    const float* energy = (const float*)d_in[4];
    const float* path   = (const float*)d_in[5];
    const float* prm[3][6];  // [dur,pit,ene] x [lng,lnb,cw,cb,ow,ob]
    for (int p = 0; p < 3; p++)
        for (int q = 0; q < 6; q++)
            prm[p][q] = (const float*)d_in[6 + p * 6 + q];

    float* out         = (float*)d_out;
    float* dur_pred    = out + (size_t)B_ * C_ * TY_;
    float* pitch_pred  = dur_pred + B_ * TX_;
    float* energy_pred = pitch_pred + B_ * TY_;

    const size_t BCTY = (size_t)B_ * C_ * TY_;
    char* w = (char*)d_ws;
    auto alloc = [&](size_t bytes) { char* r = w; w += (bytes + 255) & ~(size_t)255; return r; };

    unsigned short* W2   = (unsigned short*)alloc(6 * LAY_ * 2);
    float* biasT         = (float*)alloc(6 * 384 * 4);
    float* bc0           = (float*)alloc(6 * 384 * 4);
    float* bc2           = (float*)alloc(6 * 384 * 4);
    float2* stA          = (float2*)alloc((size_t)B_ * TY_ * 8);  // x-stats -> xe-stats
    float2* stB          = (float2*)alloc((size_t)B_ * TY_ * 8);  // dur-H stats -> pit-H stats
    float2* stC          = (float2*)alloc((size_t)B_ * TY_ * 8);  // ene-H stats
    unsigned short* x2p  = (unsigned short*)alloc((size_t)B_ * 196608 * 2);
    unsigned short* H1p  = (unsigned short*)alloc(BCTY * 2);      // also dur-H (prefix)
    unsigned short* H1d  = H1p;
    size_t base_end = (size_t)(w - (char*)d_ws);
    unsigned short* xebf = (unsigned short*)alloc(BCTY * 2);
    size_t xe_end = (size_t)(w - (char*)d_ws);
    unsigned short* H1e  = (unsigned short*)alloc(BCTY * 2);
    size_t full_end = (size_t)(w - (char*)d_ws);

    const bool haveXe = (xe_end <= ws_size);
    const bool haveE  = (full_end <= ws_size);
    if (base_end > ws_size) return;  // should not happen (round-2 proved larger fits)

    // ---- prep
    pack_w2<<<dim3((6 * 36 * 384 * 4 + 255) / 256), 256, 0, stream>>>(
        prm[0][2], prm[1][2], prm[2][2], prm[0][0], prm[1][0], prm[2][0], W2);
    bias_fold<<<dim3(9), 256, 0, stream>>>(
        prm[0][2], prm[1][2], prm[2][2], prm[0][1], prm[1][1], prm[2][1],
        prm[0][3], prm[1][3], prm[2][3], biasT, bc0, bc2);
    pack_x2<<<dim3((B_ * 16 * 384 * 4 + 255) / 256), 256, 0, stream>>>(x, x2p);
    ln_stats_f32<<<dim3(TX_ / 64, B_), 256, 0, stream>>>(x, stA, TX_);

    // ---- duration predictor (T = TX)
    conv_ln<false, false><<<dim3(256, 1, 1), 256, 0, stream>>>(
        x, 0, stA, 0, W2, biasT, bc0, bc2, 0, 0, x_mask,
        H1d, 0, stB, 0, nullptr, 0, nullptr, nullptr, nullptr, nullptr, TX_, 3, 1);
    conv_ln<true, true><<<dim3(256, 1, 1), 256, 0, stream>>>(
        H1d, 0, stB, 0, W2, biasT, bc0, bc2, 1, 0, x_mask,
        nullptr, 0, nullptr, 0, dur_pred, 0, prm[0][4], prm[0][4], prm[0][5], prm[0][5],
        TX_, 3, 1);

    // ---- length regulator
    bmm_ln<<<dim3(2048, 1, 1), 256, 0, stream>>>(
        x2p, path, pitch, energy, out, haveXe ? xebf : nullptr, stA, haveXe ? 1 : 0);

    if (haveE) {
        // L1 pair: stage LN(xe) once, compute pitch-H and energy-H
        conv_ln<true, false><<<dim3(1024, 1, 1), 256, 0, stream>>>(
            xebf, 0, stA, 0, W2, biasT, bc0, bc2, 2, 2, y_mask,
            H1p, (long)(H1e - H1p), stB, (long)(stC - stB),
            nullptr, 0, nullptr, nullptr, nullptr, nullptr, TY_, 5, 2);
        // L2 pair via grid.z
        conv_ln<true, true><<<dim3(1024, 1, 2), 256, 0, stream>>>(
            H1p, (long)(H1e - H1p), stB, (long)(stC - stB), W2, biasT, bc0, bc2,
            3, 2, y_mask, nullptr, 0, nullptr, 0,
            pitch_pred, (long)((size_t)B_ * TY_),
            prm[1][4], prm[2][4], prm[1][5], prm[2][5], TY_, 5, 1);
    } else if (haveXe) {
        for (int pr = 0; pr < 2; pr++) {
            float* pd = pr ? energy_pred : pitch_pred;
            conv_ln<true, false><<<dim3(1024, 1, 1), 256, 0, stream>>>(
                xebf, 0, stA, 0, W2, biasT, bc0, bc2, 2 + 2 * pr, 0, y_mask,
                H1p, 0, stB, 0, nullptr, 0, nullptr, nullptr, nullptr, nullptr, TY_, 5, 1);
            conv_ln<true, true><<<dim3(1024, 1, 1), 256, 0, stream>>>(
                H1p, 0, stB, 0, W2, biasT, bc0, bc2, 3 + 2 * pr, 0, y_mask,
                nullptr, 0, nullptr, 0, pd, 0,
                prm[1 + pr][4], prm[1 + pr][4], prm[1 + pr][5], prm[1 + pr][5], TY_, 5, 1);
        }
    } else {
        for (int pr = 0; pr < 2; pr++) {
            float* pd = pr ? energy_pred : pitch_pred;
            conv_ln<false, false><<<dim3(1024, 1, 1), 256, 0, stream>>>(
                out, 0, stA, 0, W2, biasT, bc0, bc2, 2 + 2 * pr, 0, y_mask,
                H1p, 0, stB, 0, nullptr, 0, nullptr, nullptr, nullptr, nullptr, TY_, 5, 1);
            conv_ln<true, true><<<dim3(1024, 1, 1), 256, 0, stream>>>(
                H1p, 0, stB, 0, W2, biasT, bc0, bc2, 3 + 2 * pr, 0, y_mask,
                nullptr, 0, nullptr, 0, pd, 0,
                prm[1 + pr][4], prm[1 + pr][4], prm[1 + pr][5], prm[1 + pr][5], TY_, 5, 1);
        }
        add3<<<dim3(2048), 256, 0, stream>>>((float4*)out, (const float4*)pitch,
                                             (const float4*)energy, B_ * C_ * TY_ / 4);
    }
}

// Round 4
// 938.038 us; speedup vs baseline: 1.3948x; 1.3948x over previous
//
#include <hip/hip_runtime.h>

#define B_ 32
#define C_ 384
#define TX_ 512
#define TY_ 2048
#define KW_ 3
#define EPS_ 1e-5f
#define LAY_ ((size_t)(36 * 1536 * 8))   // shorts per packed conv layer (442368)

typedef __attribute__((ext_vector_type(8))) short short8;
typedef __attribute__((ext_vector_type(4))) float f32x4;

#define MFMA(a, b, c) __builtin_amdgcn_mfma_f32_16x16x32_bf16(a, b, c, 0, 0, 0)

__device__ inline unsigned short f2bf(float f) {
    union { float f; unsigned int u; } v; v.f = f;
    unsigned int r = v.u + 0x7fffu + ((v.u >> 16) & 1u);
    return (unsigned short)(r >> 16);
}
__device__ inline float bf2f(unsigned short s) {
    union { float f; unsigned int u; } v; v.u = ((unsigned int)s) << 16;
    return v.f;
}

template<bool INBF>
__device__ inline float ldx(const void* p, size_t i) {
    if constexpr (INBF) return bf2f(((const unsigned short*)p)[i]);
    else return ((const float*)p)[i];
}

// ---- pack conv weights f32 [NL][O][I][K] -> fragment-linear bf16, folding LN gamma:
// granule G = ((lay*36 + c)*384 + o)*4 + lg, c = k*12+ib; elems e: W[o][i][k]*g[i],
// i = ib*32 + lg*8 + e.
__global__ __launch_bounds__(256) void pack_w2(const float* cw0, const float* cw1,
                                               const float* cw2, const float* g0,
                                               const float* g1, const float* g2,
                                               unsigned short* wp) {
    int idx = blockIdx.x * 256 + threadIdx.x;
    const int NG = 6 * 36 * 384 * 4;
    if (idx >= NG) return;
    int lg = idx & 3;
    int o = (idx >> 2) % 384;
    int c = ((idx >> 2) / 384) % 36;
    int lay = (idx >> 2) / (384 * 36);
    int k = c / 12, ib = c % 12;
    int pr = lay >> 1, l = lay & 1;
    const float* cw = ((pr == 0) ? cw0 : (pr == 1) ? cw1 : cw2) + (size_t)l * C_ * C_ * KW_;
    const float* g  = ((pr == 0) ? g0  : (pr == 1) ? g1  : g2)  + (size_t)l * C_;
    const int i0 = ib * 32 + lg * 8;
    short8 v;
    #pragma unroll
    for (int e = 0; e < 8; e++)
        v[e] = (short)f2bf(cw[((size_t)o * C_ + i0 + e) * KW_ + k] * g[i0 + e]);
    *(short8*)&wp[(size_t)idx * 8] = v;
}

// ---- fold LN beta into conv bias: biasT[lay][o] = cb[o] + sum_{i,k} W[o,i,k]*beta[i];
// bc0/bc2 hold the k=0 / k=2 partial sums for boundary-column correction.
__global__ __launch_bounds__(256) void bias_fold(
    const float* cw0, const float* cw1, const float* cw2,
    const float* be0, const float* be1, const float* be2,
    const float* cb0, const float* cb1, const float* cb2,
    float* biasT, float* bc0, float* bc2) {
    int idx = blockIdx.x * 256 + threadIdx.x;
    if (idx >= 6 * 384) return;
    int o = idx % 384, lay = idx / 384;
    int pr = lay >> 1, l = lay & 1;
    const float* cw = ((pr == 0) ? cw0 : (pr == 1) ? cw1 : cw2)
                      + (size_t)l * C_ * C_ * KW_ + (size_t)o * C_ * KW_;
    const float* be = ((pr == 0) ? be0 : (pr == 1) ? be1 : be2) + (size_t)l * C_;
    const float* cb = ((pr == 0) ? cb0 : (pr == 1) ? cb1 : cb2) + (size_t)l * C_;
    float s0 = 0.f, s1 = 0.f, s2 = 0.f;
    for (int i = 0; i < C_; i++) {
        const float b = be[i];
        s0 += cw[i * 3 + 0] * b; s1 += cw[i * 3 + 1] * b; s2 += cw[i * 3 + 2] * b;
    }
    biasT[idx] = cb[o] + s0 + s1 + s2;
    bc0[idx] = s0; bc2[idx] = s2;
}

// ---- pack x f32 [B][C][TX] -> fragment-linear bf16 for bmm A-operand
__global__ __launch_bounds__(256) void pack_x2(const float* x, unsigned short* xp) {
    int idx = blockIdx.x * 256 + threadIdx.x;
    const int NG = B_ * 16 * 384 * 4;
    if (idx >= NG) return;
    int lg = idx & 3;
    int c = (idx >> 2) % 384;
    int q = ((idx >> 2) / 384) % 16;
    int b = (idx >> 2) / (384 * 16);
    const float* src = x + ((size_t)b * C_ + c) * TX_ + q * 32 + lg * 8;
    short8 v;
    #pragma unroll
    for (int e = 0; e < 8; e++) v[e] = (short)f2bf(src[e]);
    *(short8*)&xp[(size_t)idx * 8] = v;
}

// ---- LN stats (mean, rstd) over C at each (b,t) of f32 [B,C,T]
__global__ __launch_bounds__(256) void ln_stats_f32(const float* x, float2* st, int T) {
    __shared__ float r1[4][64], r2[4][64];
    int b = blockIdx.y, t0 = blockIdx.x * 64;
    int tl = threadIdx.x & 63, g = threadIdx.x >> 6;
    int t = t0 + tl;
    const float* p = x + (size_t)b * C_ * T + t;
    float s = 0.f, ss = 0.f;
    for (int c = g; c < C_; c += 4) { float v = p[(size_t)c * T]; s += v; ss += v * v; }
    r1[g][tl] = s; r2[g][tl] = ss;
    __syncthreads();
    if (threadIdx.x < 64) {
        float s1 = r1[0][tl] + r1[1][tl] + r1[2][tl] + r1[3][tl];
        float s2 = r2[0][tl] + r2[1][tl] + r2[2][tl] + r2[3][tl];
        float m = s1 * (1.f / C_);
        float var = s2 * (1.f / C_) - m * m;
        st[(size_t)b * T + t0 + tl] = make_float2(m, rsqrtf(var + EPS_));
    }
}

// ---- fused LN(z-only) -> conv1d(K=3) -> bias' -> SiLU -> mask.  (round-2 structure;
// gamma folded into W2, beta folded into biasT, bc0/bc2 fix zero-padded edges)
template<bool INBF, bool PRED>
__global__ __launch_bounds__(256, 2) void conv_ln(
    const void* __restrict__ Xin, const float2* __restrict__ stin,
    const unsigned short* __restrict__ W2lay,
    const float* __restrict__ bT, const float* __restrict__ c0v,
    const float* __restrict__ c2v,
    const float* __restrict__ mask,
    unsigned short* __restrict__ Hout, float2* __restrict__ stout,
    float* __restrict__ pred, const float* __restrict__ ow,
    const float* __restrict__ obias, int T)
{
    __shared__ __align__(16) unsigned short xs[66 * 384];
    const int tid = threadIdx.x;
    const int b = blockIdx.y;
    const int t0 = blockIdx.x * 64;
    const int lane = tid & 63;
    const int wave = tid >> 6;
    const int lr = lane & 15, lg = lane >> 4;
    const int wm = wave * 96;

    // ---- stage z=(x-m)*rstd tile: rows tt=0..65 <-> t=t0-1+tt, swizzled 16B granules
    {
        const int tt = 1 + lane;
        const int t = t0 + lane;
        const float2 mr = stin[(size_t)b * T + t];
        for (int cg = wave; cg < 48; cg += 4) {
            const size_t base = ((size_t)b * C_ + cg * 8) * T + t;
            short8 v8;
            #pragma unroll
            for (int j = 0; j < 8; j++) {
                float v = ldx<INBF>(Xin, base + (size_t)j * T);
                v8[j] = (short)f2bf((v - mr.x) * mr.y);
            }
            const int ph = (cg & ~7) | ((cg ^ tt) & 7);
            *(short8*)&xs[tt * 384 + ph * 8] = v8;
        }
        if (tid < 96) {  // halo rows (zero-padded SAME conv)
            const int tt2 = (tid < 48) ? 0 : 65;
            const int cg = tid % 48;
            const int t2 = t0 - 1 + tt2;
            short8 v8;
            if (t2 >= 0 && t2 < T) {
                const float2 mr2 = stin[(size_t)b * T + t2];
                const size_t base = ((size_t)b * C_ + cg * 8) * T + t2;
                #pragma unroll
                for (int j = 0; j < 8; j++)
                    v8[j] = (short)f2bf((ldx<INBF>(Xin, base + (size_t)j * T) - mr2.x) * mr2.y);
            } else {
                #pragma unroll
                for (int j = 0; j < 8; j++) v8[j] = 0;
            }
            const int ph = (cg & ~7) | ((cg ^ tt2) & 7);
            *(short8*)&xs[tt2 * 384 + ph * 8] = v8;
        }
    }
    __syncthreads();

    f32x4 acc[6][4];
    const f32x4 zero = {0.f, 0.f, 0.f, 0.f};
    #pragma unroll
    for (int fm = 0; fm < 6; fm++)
        #pragma unroll
        for (int fn = 0; fn < 4; fn++) acc[fm][fn] = zero;

    const unsigned short* wbase = W2lay + (size_t)((wm + lr) * 4 + lg) * 8;
    short8 afA[6], afB[6], bfA[4], bfB[4];

    auto LOADAF = [&](short8* dst, int c) {
        #pragma unroll
        for (int fm = 0; fm < 6; fm++)
            dst[fm] = *(const short8*)(wbase + (size_t)c * 12288 + fm * 512);
    };
    auto LOADBF = [&](short8* dst, int c) {
        const int k = c / 12, ib = c - k * 12;
        #pragma unroll
        for (int fn = 0; fn < 4; fn++) {
            const int row = k + fn * 16 + lr;
            const int cgi = ib * 4 + lg;
            const int ph = (cgi & ~7) | ((cgi ^ row) & 7);
            dst[fn] = *(const short8*)&xs[row * 384 + ph * 8];
        }
    };
    auto FMAS = [&](short8* af, short8* bf) {
        #pragma unroll
        for (int fm = 0; fm < 6; fm++)
            #pragma unroll
            for (int fn = 0; fn < 4; fn++)
                acc[fm][fn] = MFMA(af[fm], bf[fn], acc[fm][fn]);
    };

    LOADAF(afA, 0); LOADBF(bfA, 0);
    #pragma unroll
    for (int c = 0; c < 36; c += 2) {
        LOADAF(afB, c + 1); LOADBF(bfB, c + 1);
        FMAS(afA, bfA);
        const int c2 = (c + 2 < 36) ? c + 2 : 35;
        LOADAF(afA, c2); LOADBF(bfA, c2);
        FMAS(afB, bfB);
    }

    // ---- epilogue
    __syncthreads();
    float* red = (float*)xs;
    if (tid < (PRED ? 64 : 128)) red[tid] = 0.f;
    __syncthreads();

    #pragma unroll
    for (int fn = 0; fn < 4; fn++) {
        const int tl = fn * 16 + lr;
        const int t = t0 + tl;
        const float mk = mask[(size_t)b * T + t];
        float s1 = 0.f, s2 = 0.f;
        #pragma unroll
        for (int fm = 0; fm < 6; fm++) {
            const int o0 = wm + fm * 16 + lg * 4;
            #pragma unroll
            for (int j = 0; j < 4; j++) {
                float h = acc[fm][fn][j] + bT[o0 + j];
                if (t == 0) h -= c0v[o0 + j];
                if (t == T - 1) h -= c2v[o0 + j];
                const float y = h * (1.f / (1.f + __expf(-h))) * mk;
                if constexpr (!PRED) {
                    Hout[((size_t)b * C_ + o0 + j) * T + t] = f2bf(y);
                    s1 += y; s2 += y * y;
                } else {
                    s1 += y * ow[o0 + j];
                }
            }
        }
        if constexpr (!PRED) {
            atomicAdd(&red[tl * 2], s1);
            atomicAdd(&red[tl * 2 + 1], s2);
        } else {
            atomicAdd(&red[tl], s1);
        }
    }
    __syncthreads();
    if (tid < 64) {
        const int t = t0 + tid;
        if constexpr (!PRED) {
            const float s1 = red[tid * 2], s2 = red[tid * 2 + 1];
            const float m = s1 * (1.f / C_);
            const float var = s2 * (1.f / C_) - m * m;
            stout[(size_t)b * T + t] = make_float2(m, rsqrtf(var + EPS_));
        } else {
            pred[(size_t)b * T + t] = (red[tid] + obias[0]) * mask[(size_t)b * T + t];
        }
    }
}

// ---- xe = x @ path (full K=512 in LDS, 32-y tiles); LN stats of xe;
// fused: out = xe+pitch+energy, xebf = bf16(xe)   (round-3 version, proven fast)
__global__ __launch_bounds__(256, 2) void bmm_ln(
    const unsigned short* __restrict__ x2, const float* __restrict__ path,
    const float* __restrict__ pitch, const float* __restrict__ energy,
    float* __restrict__ out, unsigned short* __restrict__ xebf,
    float2* __restrict__ stout, int fused)
{
    __shared__ __align__(16) unsigned short ps[32 * 512];   // 32 KB
    const int tid = threadIdx.x;
    const int bid = blockIdx.x;
    const int work = (bid & 7) * 256 + (bid >> 3);          // XCD-chunked swizzle
    const int b = work >> 6;
    const int y0 = (work & 63) << 5;
    const int lane = tid & 63;
    const int wave = tid >> 6;
    const int lr = lane & 15, lg = lane >> 4;
    const int wm = wave * 96;

    // ---- stage path [512 t x 32 y] -> rows y, cols t (bf16, swizzled granules)
    {
        const int yy = lane & 31;
        const int half = lane >> 5;
        const int gbase = (wave * 2 + half) * 8;
        const float* pb = path + (size_t)b * TX_ * TY_ + y0 + yy;
        #pragma unroll
        for (int h = 0; h < 2; ++h) {
            float vv[4][8];
            #pragma unroll
            for (int i = 0; i < 4; i++) {
                const int cg = gbase + h * 4 + i;
                #pragma unroll
                for (int j = 0; j < 8; j++) vv[i][j] = pb[(size_t)(cg * 8 + j) * TY_];
            }
            #pragma unroll
            for (int i = 0; i < 4; i++) {
                const int cg = gbase + h * 4 + i;
                short8 v8;
                #pragma unroll
                for (int j = 0; j < 8; j++) v8[j] = (short)f2bf(vv[i][j]);
                const int ph = (cg & ~7) | ((cg ^ yy) & 7);
                *(short8*)&ps[yy * 512 + ph * 8] = v8;
            }
        }
    }
    __syncthreads();

    f32x4 acc[6][2];
    const f32x4 zero = {0.f, 0.f, 0.f, 0.f};
    #pragma unroll
    for (int fm = 0; fm < 6; fm++) { acc[fm][0] = zero; acc[fm][1] = zero; }

    const unsigned short* xb = x2 + ((size_t)b * 16 * 1536 + (size_t)((wm + lr) * 4 + lg)) * 8;
    short8 afA[6], afB[6], bfA[2], bfB[2];

    auto LOADAF = [&](short8* dst, int q) {
        #pragma unroll
        for (int fm = 0; fm < 6; fm++)
            dst[fm] = *(const short8*)(xb + (size_t)q * 12288 + fm * 512);
    };
    auto LOADBF = [&](short8* dst, int u) {
        #pragma unroll
        for (int fn = 0; fn < 2; fn++) {
            const int row = fn * 16 + lr;
            const int cgi = u * 4 + lg;
            const int ph = (cgi & ~7) | ((cgi ^ row) & 7);
            dst[fn] = *(const short8*)&ps[row * 512 + ph * 8];
        }
    };
    auto FMAS = [&](short8* af, short8* bf) {
        #pragma unroll
        for (int fm = 0; fm < 6; fm++) {
            acc[fm][0] = MFMA(af[fm], bf[0], acc[fm][0]);
            acc[fm][1] = MFMA(af[fm], bf[1], acc[fm][1]);
        }
    };

    LOADAF(afA, 0); LOADBF(bfA, 0);
    #pragma unroll
    for (int u = 0; u < 16; u += 2) {
        LOADAF(afB, u + 1); LOADBF(bfB, u + 1);
        FMAS(afA, bfA);
        const int u2 = (u + 2 < 16) ? u + 2 : 15;
        LOADAF(afA, u2); LOADBF(bfA, u2);
        FMAS(afB, bfB);
    }

    // ---- epilogue
    __syncthreads();
    float* red = (float*)ps;
    if (tid < 64) red[tid] = 0.f;
    __syncthreads();

    #pragma unroll
    for (int fn = 0; fn < 2; fn++) {
        const int yl = fn * 16 + lr;
        const int y = y0 + yl;
        float s1 = 0.f, s2 = 0.f;
        #pragma unroll
        for (int fm = 0; fm < 6; fm++) {
            #pragma unroll
            for (int j = 0; j < 4; j++) {
                const int c = wm + fm * 16 + lg * 4 + j;
                const size_t gi = ((size_t)b * C_ + c) * TY_ + y;
                const float v = acc[fm][fn][j];
                if (fused) {
                    out[gi] = v + pitch[gi] + energy[gi];
                    xebf[gi] = f2bf(v);
                } else {
                    out[gi] = v;
                }
                s1 += v; s2 += v * v;
            }
        }
        atomicAdd(&red[yl * 2], s1);
        atomicAdd(&red[yl * 2 + 1], s2);
    }
    __syncthreads();
    if (tid < 32) {
        const int y = y0 + tid;
        const float s1 = red[tid * 2], s2 = red[tid * 2 + 1];
        const float m = s1 * (1.f / C_);
        const float var = s2 * (1.f / C_) - m * m;
        stout[(size_t)b * TY_ + y] = make_float2(m, rsqrtf(var + EPS_));
    }
}

// ---- out = xe(in place) + pitch + energy   (fallback only)
__global__ __launch_bounds__(256) void add3(float4* o, const float4* p, const float4* e, int n4) {
    for (int i = blockIdx.x * 256 + threadIdx.x; i < n4; i += gridDim.x * 256) {
        float4 a = o[i], x1 = p[i], x2 = e[i];
        a.x += x1.x + x2.x; a.y += x1.y + x2.y;
        a.z += x1.z + x2.z; a.w += x1.w + x2.w;
        o[i] = a;
    }
}

extern "C" void kernel_launch(void* const* d_in, const int* in_sizes, int n_in,
                              void* d_out, int out_size, void* d_ws, size_t ws_size,
                              hipStream_t stream)
{
    const float* x      = (const float*)d_in[0];
    const float* x_mask = (const float*)d_in[1];
    const float* y_mask = (const float*)d_in[2];
    const float* pitch  = (const float*)d_in[3];
    const float* energy = (const float*)d_in[4];
    const float* path   = (const float*)d_in[5];
    const float* prm[3][6];  // [dur,pit,ene] x [lng,lnb,cw,cb,ow,ob]
    for (int p = 0; p < 3; p++)
        for (int q = 0; q < 6; q++)
            prm[p][q] = (const float*)d_in[6 + p * 6 + q];

    float* out         = (float*)d_out;
    float* dur_pred    = out + (size_t)B_ * C_ * TY_;
    float* pitch_pred  = dur_pred + B_ * TX_;
    float* energy_pred = pitch_pred + B_ * TY_;

    const size_t BCTY = (size_t)B_ * C_ * TY_;
    char* w = (char*)d_ws;
    auto alloc = [&](size_t bytes) { char* r = w; w += (bytes + 255) & ~(size_t)255; return r; };

    unsigned short* W2   = (unsigned short*)alloc(6 * LAY_ * 2);
    float* biasT         = (float*)alloc(6 * 384 * 4);
    float* bc0           = (float*)alloc(6 * 384 * 4);
    float* bc2           = (float*)alloc(6 * 384 * 4);
    float2* stA          = (float2*)alloc((size_t)B_ * TY_ * 8);  // x-stats -> xe-stats
    float2* stB          = (float2*)alloc((size_t)B_ * TY_ * 8);  // H stats
    unsigned short* x2p  = (unsigned short*)alloc((size_t)B_ * 196608 * 2);
    unsigned short* H1   = (unsigned short*)alloc(BCTY * 2);
    size_t base_end = (size_t)(w - (char*)d_ws);
    unsigned short* xebf = (unsigned short*)alloc(BCTY * 2);
    size_t xe_end = (size_t)(w - (char*)d_ws);

    const bool haveXe = (xe_end <= ws_size);
    if (base_end > ws_size) return;

    // ---- prep
    pack_w2<<<dim3((6 * 36 * 384 * 4 + 255) / 256), 256, 0, stream>>>(
        prm[0][2], prm[1][2], prm[2][2], prm[0][0], prm[1][0], prm[2][0], W2);
    bias_fold<<<dim3(9), 256, 0, stream>>>(
        prm[0][2], prm[1][2], prm[2][2], prm[0][1], prm[1][1], prm[2][1],
        prm[0][3], prm[1][3], prm[2][3], biasT, bc0, bc2);
    pack_x2<<<dim3((B_ * 16 * 384 * 4 + 255) / 256), 256, 0, stream>>>(x, x2p);
    ln_stats_f32<<<dim3(TX_ / 64, B_), 256, 0, stream>>>(x, stA, TX_);

    // ---- duration predictor (T = TX, input x f32)
    conv_ln<false, false><<<dim3(TX_ / 64, B_), 256, 0, stream>>>(
        x, stA, W2, biasT, bc0, bc2, x_mask, H1, stB,
        nullptr, nullptr, nullptr, TX_);
    conv_ln<true, true><<<dim3(TX_ / 64, B_), 256, 0, stream>>>(
        H1, stB, W2 + LAY_, biasT + 384, bc0 + 384, bc2 + 384, x_mask, nullptr, nullptr,
        dur_pred, prm[0][4], prm[0][5], TX_);

    // ---- length regulator (writes out = xe+pitch+energy, xebf, stA)
    bmm_ln<<<dim3(2048, 1, 1), 256, 0, stream>>>(
        x2p, path, pitch, energy, out, haveXe ? xebf : nullptr, stA, haveXe ? 1 : 0);

    if (haveXe) {
        for (int pr = 0; pr < 2; pr++) {
            float* pd = pr ? energy_pred : pitch_pred;
            const int lay = 2 + 2 * pr;
            conv_ln<true, false><<<dim3(TY_ / 64, B_), 256, 0, stream>>>(
                xebf, stA, W2 + lay * LAY_, biasT + lay * 384, bc0 + lay * 384,
                bc2 + lay * 384, y_mask, H1, stB, nullptr, nullptr, nullptr, TY_);
            conv_ln<true, true><<<dim3(TY_ / 64, B_), 256, 0, stream>>>(
                H1, stB, W2 + (lay + 1) * LAY_, biasT + (lay + 1) * 384,
                bc0 + (lay + 1) * 384, bc2 + (lay + 1) * 384, y_mask, nullptr, nullptr,
                pd, prm[1 + pr][4], prm[1 + pr][5], TY_);
        }
    } else {
        for (int pr = 0; pr < 2; pr++) {
            float* pd = pr ? energy_pred : pitch_pred;
            const int lay = 2 + 2 * pr;
            conv_ln<false, false><<<dim3(TY_ / 64, B_), 256, 0, stream>>>(
                out, stA, W2 + lay * LAY_, biasT + lay * 384, bc0 + lay * 384,
                bc2 + lay * 384, y_mask, H1, stB, nullptr, nullptr, nullptr, TY_);
            conv_ln<true, true><<<dim3(TY_ / 64, B_), 256, 0, stream>>>(
                H1, stB, W2 + (lay + 1) * LAY_, biasT + (lay + 1) * 384,
                bc0 + (lay + 1) * 384, bc2 + (lay + 1) * 384, y_mask, nullptr, nullptr,
                pd, prm[1 + pr][4], prm[1 + pr][5], TY_);
        }
        add3<<<dim3(2048), 256, 0, stream>>>((float4*)out, (const float4*)pitch,
                                             (const float4*)energy, B_ * C_ * TY_ / 4);
    }
}

// Round 6
// 745.830 us; speedup vs baseline: 1.7542x; 1.2577x over previous
//
#include <hip/hip_runtime.h>

#define B_ 32
#define C_ 384
#define TX_ 512
#define TY_ 2048
#define KW_ 3
#define EPS_ 1e-5f
#define LAY_ ((size_t)(36 * 1536 * 8))   // shorts per packed conv layer (442368)

typedef __attribute__((ext_vector_type(8))) short short8;
typedef __attribute__((ext_vector_type(4))) float f32x4;

#define MFMA(a, b, c) __builtin_amdgcn_mfma_f32_16x16x32_bf16(a, b, c, 0, 0, 0)

#define WAITV(N) do { asm volatile("s_waitcnt vmcnt(" #N ")"); \
                      __builtin_amdgcn_sched_barrier(0); } while (0)
#define WAITL()  do { asm volatile("s_waitcnt lgkmcnt(0)"); \
                      __builtin_amdgcn_sched_barrier(0); } while (0)

typedef unsigned int u32;
// async global->LDS, 16B per lane; LDS dest = lptr + lane*16 (wave-uniform base)
__device__ __forceinline__ void gl_lds16(const void* g, void* l) {
    __builtin_amdgcn_global_load_lds(
        (const __attribute__((address_space(1))) u32*)g,
        (__attribute__((address_space(3))) u32*)l, 16, 0, 0);
}

__device__ inline unsigned short f2bf(float f) {
    union { float f; unsigned int u; } v; v.f = f;
    unsigned int r = v.u + 0x7fffu + ((v.u >> 16) & 1u);
    return (unsigned short)(r >> 16);
}
__device__ inline float bf2f(unsigned short s) {
    union { float f; unsigned int u; } v; v.u = ((unsigned int)s) << 16;
    return v.f;
}

template<bool INBF>
__device__ inline float ldx(const void* p, size_t i) {
    if constexpr (INBF) return bf2f(((const unsigned short*)p)[i]);
    else return ((const float*)p)[i];
}

// ---- pack conv weights f32 [NL][O][I][K] -> fragment-linear bf16, folding LN gamma:
// granule G = ((lay*36 + c)*384 + o)*4 + lg, c = k*12+ib; elems e: W[o][i][k]*g[i],
// i = ib*32 + lg*8 + e.
__global__ __launch_bounds__(256) void pack_w2(const float* cw0, const float* cw1,
                                               const float* cw2, const float* g0,
                                               const float* g1, const float* g2,
                                               unsigned short* wp) {
    int idx = blockIdx.x * 256 + threadIdx.x;
    const int NG = 6 * 36 * 384 * 4;
    if (idx >= NG) return;
    int lg = idx & 3;
    int o = (idx >> 2) % 384;
    int c = ((idx >> 2) / 384) % 36;
    int lay = (idx >> 2) / (384 * 36);
    int k = c / 12, ib = c % 12;
    int pr = lay >> 1, l = lay & 1;
    const float* cw = ((pr == 0) ? cw0 : (pr == 1) ? cw1 : cw2) + (size_t)l * C_ * C_ * KW_;
    const float* g  = ((pr == 0) ? g0  : (pr == 1) ? g1  : g2)  + (size_t)l * C_;
    const int i0 = ib * 32 + lg * 8;
    short8 v;
    #pragma unroll
    for (int e = 0; e < 8; e++)
        v[e] = (short)f2bf(cw[((size_t)o * C_ + i0 + e) * KW_ + k] * g[i0 + e]);
    *(short8*)&wp[(size_t)idx * 8] = v;
}

// ---- fold LN beta into conv bias (+ k=0/k=2 edge corrections)
__global__ __launch_bounds__(256) void bias_fold(
    const float* cw0, const float* cw1, const float* cw2,
    const float* be0, const float* be1, const float* be2,
    const float* cb0, const float* cb1, const float* cb2,
    float* biasT, float* bc0, float* bc2) {
    int idx = blockIdx.x * 256 + threadIdx.x;
    if (idx >= 6 * 384) return;
    int o = idx % 384, lay = idx / 384;
    int pr = lay >> 1, l = lay & 1;
    const float* cw = ((pr == 0) ? cw0 : (pr == 1) ? cw1 : cw2)
                      + (size_t)l * C_ * C_ * KW_ + (size_t)o * C_ * KW_;
    const float* be = ((pr == 0) ? be0 : (pr == 1) ? be1 : be2) + (size_t)l * C_;
    const float* cb = ((pr == 0) ? cb0 : (pr == 1) ? cb1 : cb2) + (size_t)l * C_;
    float s0 = 0.f, s1 = 0.f, s2 = 0.f;
    for (int i = 0; i < C_; i++) {
        const float b = be[i];
        s0 += cw[i * 3 + 0] * b; s1 += cw[i * 3 + 1] * b; s2 += cw[i * 3 + 2] * b;
    }
    biasT[idx] = cb[o] + s0 + s1 + s2;
    bc0[idx] = s0; bc2[idx] = s2;
}

// ---- pack x f32 [B][C][TX] -> fragment-linear bf16 for bmm A-operand
__global__ __launch_bounds__(256) void pack_x2(const float* x, unsigned short* xp) {
    int idx = blockIdx.x * 256 + threadIdx.x;
    const int NG = B_ * 16 * 384 * 4;
    if (idx >= NG) return;
    int lg = idx & 3;
    int c = (idx >> 2) % 384;
    int q = ((idx >> 2) / 384) % 16;
    int b = (idx >> 2) / (384 * 16);
    const float* src = x + ((size_t)b * C_ + c) * TX_ + q * 32 + lg * 8;
    short8 v;
    #pragma unroll
    for (int e = 0; e < 8; e++) v[e] = (short)f2bf(src[e]);
    *(short8*)&xp[(size_t)idx * 8] = v;
}

// ---- LN stats (mean, rstd) over C at each (b,t) of f32 [B,C,T]
__global__ __launch_bounds__(256) void ln_stats_f32(const float* x, float2* st, int T) {
    __shared__ float r1[4][64], r2[4][64];
    int b = blockIdx.y, t0 = blockIdx.x * 64;
    int tl = threadIdx.x & 63, g = threadIdx.x >> 6;
    int t = t0 + tl;
    const float* p = x + (size_t)b * C_ * T + t;
    float s = 0.f, ss = 0.f;
    for (int c = g; c < C_; c += 4) { float v = p[(size_t)c * T]; s += v; ss += v * v; }
    r1[g][tl] = s; r2[g][tl] = ss;
    __syncthreads();
    if (threadIdx.x < 64) {
        float s1 = r1[0][tl] + r1[1][tl] + r1[2][tl] + r1[3][tl];
        float s2 = r2[0][tl] + r2[1][tl] + r2[2][tl] + r2[3][tl];
        float m = s1 * (1.f / C_);
        float var = s2 * (1.f / C_) - m * m;
        st[(size_t)b * T + t0 + tl] = make_float2(m, rsqrtf(var + EPS_));
    }
}

// ---- fused LN(z-only) -> conv1d(K=3) -> bias' -> SiLU -> mask.
// 8 waves x (48 o x 64 t). A-operand (W) streamed via wave-private LDS
// double-buffer (global_load_lds, counted vmcnt, no barriers in K-loop).
template<bool INBF, bool PRED>
__global__ __launch_bounds__(512, 2) void conv_ln(
    const void* __restrict__ Xin, const float2* __restrict__ stin,
    const unsigned short* __restrict__ W2lay,
    const float* __restrict__ bT, const float* __restrict__ c0v,
    const float* __restrict__ c2v,
    const float* __restrict__ mask,
    unsigned short* __restrict__ Hout, float2* __restrict__ stout,
    float* __restrict__ pred, const float* __restrict__ ow,
    const float* __restrict__ obias, int T)
{
    __shared__ __align__(16) unsigned short xs[66 * 384];        // 50688 B
    __shared__ __align__(16) unsigned short wlds[8][2][1536];    // 49152 B
    const int tid = threadIdx.x;
    const int b = blockIdx.y;
    const int t0 = blockIdx.x * 64;
    const int lane = tid & 63;
    const int wave = tid >> 6;
    const int lr = lane & 15, lg = lane >> 4;
    const int wm = wave * 48;

    // per-lane W source base (fragment-linear pack; lane i's 16B -> LDS slot i)
    const unsigned short* gbw = W2lay + (size_t)(wm * 4 + lr * 4 + lg) * 8;
    auto STAGE = [&](int c, int buf) {
        #pragma unroll
        for (int fm = 0; fm < 3; fm++)
            gl_lds16(gbw + (size_t)c * 12288 + fm * 512, &wlds[wave][buf][fm * 512]);
    };
    STAGE(0, 0);
    STAGE(1, 1);

    // ---- stage z=(x-m)*rstd tile: rows tt=0..65 <-> t=t0-1+tt, swizzled 16B granules
    {
        const int tt = 1 + lane;
        const int t = t0 + lane;
        const float2 mr = stin[(size_t)b * T + t];
        for (int cg = wave; cg < 48; cg += 8) {
            const size_t base = ((size_t)b * C_ + cg * 8) * T + t;
            short8 v8;
            #pragma unroll
            for (int j = 0; j < 8; j++) {
                float v = ldx<INBF>(Xin, base + (size_t)j * T);
                v8[j] = (short)f2bf((v - mr.x) * mr.y);
            }
            const int ph = (cg & ~7) | ((cg ^ tt) & 7);
            *(short8*)&xs[tt * 384 + ph * 8] = v8;
        }
        if (tid < 96) {  // halo rows (zero-padded SAME conv)
            const int tt2 = (tid < 48) ? 0 : 65;
            const int cg = tid % 48;
            const int t2 = t0 - 1 + tt2;
            short8 v8;
            if (t2 >= 0 && t2 < T) {
                const float2 mr2 = stin[(size_t)b * T + t2];
                const size_t base = ((size_t)b * C_ + cg * 8) * T + t2;
                #pragma unroll
                for (int j = 0; j < 8; j++)
                    v8[j] = (short)f2bf((ldx<INBF>(Xin, base + (size_t)j * T) - mr2.x) * mr2.y);
            } else {
                #pragma unroll
                for (int j = 0; j < 8; j++) v8[j] = 0;
            }
            const int ph = (cg & ~7) | ((cg ^ tt2) & 7);
            *(short8*)&xs[tt2 * 384 + ph * 8] = v8;
        }
    }
    __syncthreads();   // drains all vmcnt: buf0/buf1 landed, xs visible

    f32x4 acc[3][4];
    const f32x4 zero = {0.f, 0.f, 0.f, 0.f};
    #pragma unroll
    for (int fm = 0; fm < 3; fm++)
        #pragma unroll
        for (int fn = 0; fn < 4; fn++) acc[fm][fn] = zero;

    for (int c = 0; c < 36; ++c) {
        WAITV(3);          // step c's 3 DMAs landed (c+1's may be in flight)
        short8 af[3], bf[4];
        #pragma unroll
        for (int fm = 0; fm < 3; fm++)
            af[fm] = *(const short8*)&wlds[wave][c & 1][fm * 512 + lane * 8];
        {
            const int k = c / 12, ib = c - k * 12;
            #pragma unroll
            for (int fn = 0; fn < 4; fn++) {
                const int row = k + fn * 16 + lr;
                const int cgi = ib * 4 + lg;
                const int ph = (cgi & ~7) | ((cgi ^ row) & 7);
                bf[fn] = *(const short8*)&xs[row * 384 + ph * 8];
            }
        }
        WAITL();           // af/bf in regs; safe to overwrite buf[c&1]
        if (c + 2 < 36) STAGE(c + 2, c & 1);
        __builtin_amdgcn_sched_barrier(0);
        __builtin_amdgcn_s_setprio(1);
        #pragma unroll
        for (int fm = 0; fm < 3; fm++)
            #pragma unroll
            for (int fn = 0; fn < 4; fn++)
                acc[fm][fn] = MFMA(af[fm], bf[fn], acc[fm][fn]);
        __builtin_amdgcn_s_setprio(0);
    }
    WAITV(0);

    // ---- epilogue
    __syncthreads();
    float* red = (float*)xs;
    if (tid < (PRED ? 64 : 128)) red[tid] = 0.f;
    __syncthreads();

    #pragma unroll
    for (int fn = 0; fn < 4; fn++) {
        const int tl = fn * 16 + lr;
        const int t = t0 + tl;
        const float mk = mask[(size_t)b * T + t];
        float s1 = 0.f, s2 = 0.f;
        #pragma unroll
        for (int fm = 0; fm < 3; fm++) {
            const int o0 = wm + fm * 16 + lg * 4;
            #pragma unroll
            for (int j = 0; j < 4; j++) {
                float h = acc[fm][fn][j] + bT[o0 + j];
                if (t == 0) h -= c0v[o0 + j];
                if (t == T - 1) h -= c2v[o0 + j];
                const float y = h * (1.f / (1.f + __expf(-h))) * mk;
                if constexpr (!PRED) {
                    Hout[((size_t)b * C_ + o0 + j) * T + t] = f2bf(y);
                    s1 += y; s2 += y * y;
                } else {
                    s1 += y * ow[o0 + j];
                }
            }
        }
        if constexpr (!PRED) {
            atomicAdd(&red[tl * 2], s1);
            atomicAdd(&red[tl * 2 + 1], s2);
        } else {
            atomicAdd(&red[tl], s1);
        }
    }
    __syncthreads();
    if (tid < 64) {
        const int t = t0 + tid;
        if constexpr (!PRED) {
            const float s1 = red[tid * 2], s2 = red[tid * 2 + 1];
            const float m = s1 * (1.f / C_);
            const float var = s2 * (1.f / C_) - m * m;
            stout[(size_t)b * T + t] = make_float2(m, rsqrtf(var + EPS_));
        } else {
            pred[(size_t)b * T + t] = (red[tid] + obias[0]) * mask[(size_t)b * T + t];
        }
    }
}

// ---- xe = x @ path (full K=512 path tile in LDS, 64-y tiles, 8 waves);
// A-operand (x2p) via wave-private LDS double-buffer. LN stats of xe;
// fused: out = xe+pitch+energy, xebf = bf16(xe)
__global__ __launch_bounds__(512, 2) void bmm_ln(
    const unsigned short* __restrict__ x2, const float* __restrict__ path,
    const float* __restrict__ pitch, const float* __restrict__ energy,
    float* __restrict__ out, unsigned short* __restrict__ xebf,
    float2* __restrict__ stout, int fused)
{
    __shared__ __align__(16) unsigned short ps[64 * 512];        // 65536 B
    __shared__ __align__(16) unsigned short wlds[8][2][1536];    // 49152 B
    const int tid = threadIdx.x;
    const int bid = blockIdx.x;
    const int work = (bid & 7) * 128 + (bid >> 3);   // XCD-chunked swizzle (1024)
    const int b = work >> 5;
    const int y0 = (work & 31) << 6;
    const int lane = tid & 63;
    const int wave = tid >> 6;
    const int lr = lane & 15, lg = lane >> 4;
    const int wm = wave * 48;

    const unsigned short* gbx = x2 + ((size_t)b * 16 * 1536 + wm * 4 + lr * 4 + lg) * 8;
    auto STAGE = [&](int u, int buf) {
        #pragma unroll
        for (int fm = 0; fm < 3; fm++)
            gl_lds16(gbx + (size_t)u * 12288 + fm * 512, &wlds[wave][buf][fm * 512]);
    };
    STAGE(0, 0);
    STAGE(1, 1);

    // ---- stage path [512 t x 64 y] -> rows y, cols t (bf16, swizzled granules)
    {
        const int yy = lane;
        const float* pb = path + (size_t)b * TX_ * TY_ + y0 + yy;
        for (int i = 0; i < 8; i++) {
            const int cg = wave + 8 * i;
            short8 v8;
            #pragma unroll
            for (int j = 0; j < 8; j++) v8[j] = (short)f2bf(pb[(size_t)(cg * 8 + j) * TY_]);
            const int ph = (cg & ~7) | ((cg ^ yy) & 7);
            *(short8*)&ps[yy * 512 + ph * 8] = v8;
        }
    }
    __syncthreads();   // drains vmcnt: buf0/buf1 landed, ps visible

    f32x4 acc[3][4];
    const f32x4 zero = {0.f, 0.f, 0.f, 0.f};
    #pragma unroll
    for (int fm = 0; fm < 3; fm++)
        #pragma unroll
        for (int fn = 0; fn < 4; fn++) acc[fm][fn] = zero;

    for (int u = 0; u < 16; ++u) {
        WAITV(3);
        short8 af[3], bf[4];
        #pragma unroll
        for (int fm = 0; fm < 3; fm++)
            af[fm] = *(const short8*)&wlds[wave][u & 1][fm * 512 + lane * 8];
        #pragma unroll
        for (int fn = 0; fn < 4; fn++) {
            const int row = fn * 16 + lr;
            const int cgi = u * 4 + lg;
            const int ph = (cgi & ~7) | ((cgi ^ row) & 7);
            bf[fn] = *(const short8*)&ps[row * 512 + ph * 8];
        }
        WAITL();
        if (u + 2 < 16) STAGE(u + 2, u & 1);
        __builtin_amdgcn_sched_barrier(0);
        __builtin_amdgcn_s_setprio(1);
        #pragma unroll
        for (int fm = 0; fm < 3; fm++)
            #pragma unroll
            for (int fn = 0; fn < 4; fn++)
                acc[fm][fn] = MFMA(af[fm], bf[fn], acc[fm][fn]);
        __builtin_amdgcn_s_setprio(0);
    }
    WAITV(0);

    // ---- epilogue
    __syncthreads();
    float* red = (float*)ps;
    if (tid < 128) red[tid] = 0.f;
    __syncthreads();

    #pragma unroll
    for (int fn = 0; fn < 4; fn++) {
        const int yl = fn * 16 + lr;
        const int y = y0 + yl;
        float s1 = 0.f, s2 = 0.f;
        #pragma unroll
        for (int fm = 0; fm < 3; fm++) {
            #pragma unroll
            for (int j = 0; j < 4; j++) {
                const int c = wm + fm * 16 + lg * 4 + j;
                const size_t gi = ((size_t)b * C_ + c) * TY_ + y;
                const float v = acc[fm][fn][j];
                if (fused) {
                    out[gi] = v + pitch[gi] + energy[gi];
                    xebf[gi] = f2bf(v);
                } else {
                    out[gi] = v;
                }
                s1 += v; s2 += v * v;
            }
        }
        atomicAdd(&red[yl * 2], s1);
        atomicAdd(&red[yl * 2 + 1], s2);
    }
    __syncthreads();
    if (tid < 64) {
        const int y = y0 + tid;
        const float s1 = red[tid * 2], s2 = red[tid * 2 + 1];
        const float m = s1 * (1.f / C_);
        const float var = s2 * (1.f / C_) - m * m;
        stout[(size_t)b * TY_ + y] = make_float2(m, rsqrtf(var + EPS_));
    }
}

// ---- out = xe(in place) + pitch + energy   (fallback only)
__global__ __launch_bounds__(256) void add3(float4* o, const float4* p, const float4* e, int n4) {
    for (int i = blockIdx.x * 256 + threadIdx.x; i < n4; i += gridDim.x * 256) {
        float4 a = o[i], x1 = p[i], x2 = e[i];
        a.x += x1.x + x2.x; a.y += x1.y + x2.y;
        a.z += x1.z + x2.z; a.w += x1.w + x2.w;
        o[i] = a;
    }
}

extern "C" void kernel_launch(void* const* d_in, const int* in_sizes, int n_in,
                              void* d_out, int out_size, void* d_ws, size_t ws_size,
                              hipStream_t stream)
{
    const float* x      = (const float*)d_in[0];
    const float* x_mask = (const float*)d_in[1];
    const float* y_mask = (const float*)d_in[2];
    const float* pitch  = (const float*)d_in[3];
    const float* energy = (const float*)d_in[4];
    const float* path   = (const float*)d_in[5];
    const float* prm[3][6];  // [dur,pit,ene] x [lng,lnb,cw,cb,ow,ob]
    for (int p = 0; p < 3; p++)
        for (int q = 0; q < 6; q++)
            prm[p][q] = (const float*)d_in[6 + p * 6 + q];

    float* out         = (float*)d_out;
    float* dur_pred    = out + (size_t)B_ * C_ * TY_;
    float* pitch_pred  = dur_pred + B_ * TX_;
    float* energy_pred = pitch_pred + B_ * TY_;

    const size_t BCTY = (size_t)B_ * C_ * TY_;
    char* w = (char*)d_ws;
    auto alloc = [&](size_t bytes) { char* r = w; w += (bytes + 255) & ~(size_t)255; return r; };

    unsigned short* W2   = (unsigned short*)alloc(6 * LAY_ * 2);
    float* biasT         = (float*)alloc(6 * 384 * 4);
    float* bc0           = (float*)alloc(6 * 384 * 4);
    float* bc2           = (float*)alloc(6 * 384 * 4);
    float2* stA          = (float2*)alloc((size_t)B_ * TY_ * 8);  // x-stats -> xe-stats
    float2* stB          = (float2*)alloc((size_t)B_ * TY_ * 8);  // H stats
    unsigned short* x2p  = (unsigned short*)alloc((size_t)B_ * 196608 * 2);
    unsigned short* H1   = (unsigned short*)alloc(BCTY * 2);
    size_t base_end = (size_t)(w - (char*)d_ws);
    unsigned short* xebf = (unsigned short*)alloc(BCTY * 2);
    size_t xe_end = (size_t)(w - (char*)d_ws);

    const bool haveXe = (xe_end <= ws_size);
    if (base_end > ws_size) return;

    // ---- prep
    pack_w2<<<dim3((6 * 36 * 384 * 4 + 255) / 256), 256, 0, stream>>>(
        prm[0][2], prm[1][2], prm[2][2], prm[0][0], prm[1][0], prm[2][0], W2);
    bias_fold<<<dim3(9), 256, 0, stream>>>(
        prm[0][2], prm[1][2], prm[2][2], prm[0][1], prm[1][1], prm[2][1],
        prm[0][3], prm[1][3], prm[2][3], biasT, bc0, bc2);
    pack_x2<<<dim3((B_ * 16 * 384 * 4 + 255) / 256), 256, 0, stream>>>(x, x2p);
    ln_stats_f32<<<dim3(TX_ / 64, B_), 256, 0, stream>>>(x, stA, TX_);

    // ---- duration predictor (T = TX, input x f32)
    conv_ln<false, false><<<dim3(TX_ / 64, B_), 512, 0, stream>>>(
        x, stA, W2, biasT, bc0, bc2, x_mask, H1, stB,
        nullptr, nullptr, nullptr, TX_);
    conv_ln<true, true><<<dim3(TX_ / 64, B_), 512, 0, stream>>>(
        H1, stB, W2 + LAY_, biasT + 384, bc0 + 384, bc2 + 384, x_mask, nullptr, nullptr,
        dur_pred, prm[0][4], prm[0][5], TX_);

    // ---- length regulator (writes out = xe+pitch+energy, xebf, stA)
    bmm_ln<<<dim3(1024, 1, 1), 512, 0, stream>>>(
        x2p, path, pitch, energy, out, haveXe ? xebf : nullptr, stA, haveXe ? 1 : 0);

    if (haveXe) {
        for (int pr = 0; pr < 2; pr++) {
            float* pd = pr ? energy_pred : pitch_pred;
            const int lay = 2 + 2 * pr;
            conv_ln<true, false><<<dim3(TY_ / 64, B_), 512, 0, stream>>>(
                xebf, stA, W2 + lay * LAY_, biasT + lay * 384, bc0 + lay * 384,
                bc2 + lay * 384, y_mask, H1, stB, nullptr, nullptr, nullptr, TY_);
            conv_ln<true, true><<<dim3(TY_ / 64, B_), 512, 0, stream>>>(
                H1, stB, W2 + (lay + 1) * LAY_, biasT + (lay + 1) * 384,
                bc0 + (lay + 1) * 384, bc2 + (lay + 1) * 384, y_mask, nullptr, nullptr,
                pd, prm[1 + pr][4], prm[1 + pr][5], TY_);
        }
    } else {
        for (int pr = 0; pr < 2; pr++) {
            float* pd = pr ? energy_pred : pitch_pred;
            const int lay = 2 + 2 * pr;
            conv_ln<false, false><<<dim3(TY_ / 64, B_), 512, 0, stream>>>(
                out, stA, W2 + lay * LAY_, biasT + lay * 384, bc0 + lay * 384,
                bc2 + lay * 384, y_mask, H1, stB, nullptr, nullptr, nullptr, TY_);
            conv_ln<true, true><<<dim3(TY_ / 64, B_), 512, 0, stream>>>(
                H1, stB, W2 + (lay + 1) * LAY_, biasT + (lay + 1) * 384,
                bc0 + (lay + 1) * 384, bc2 + (lay + 1) * 384, y_mask, nullptr, nullptr,
                pd, prm[1 + pr][4], prm[1 + pr][5], TY_);
        }
        add3<<<dim3(2048), 256, 0, stream>>>((float4*)out, (const float4*)pitch,
                                             (const float4*)energy, B_ * C_ * TY_ / 4);
    }
}